// Round 4
// baseline (1291.895 us; speedup 1.0000x reference)
//
#include <hip/hip_runtime.h>

#define VOCAB_N 50265
#define NPAD    50304
#define KX      832     // padded D_CAT (784 -> 13*64)
#define DEMB    768
#define DCAT    784
#define SEQ     512
#define NBATCH  4
#define OUT_ROWS 2048

typedef unsigned short u16;
typedef unsigned long long u64;
typedef short s16x8 __attribute__((ext_vector_type(8)));
typedef float f32x4 __attribute__((ext_vector_type(4)));
typedef u16   u16x4 __attribute__((ext_vector_type(4)));

#define AS1 __attribute__((address_space(1)))
#define AS3 __attribute__((address_space(3)))

__device__ __forceinline__ u16 f2bf(float f){
  unsigned u = __builtin_bit_cast(unsigned, f);
  u = (u + 0x7FFFu + ((u >> 16) & 1u)) >> 16;
  return (u16)u;
}

__device__ __forceinline__ void gl_lds16(const void* g, void* l){
  __builtin_amdgcn_global_load_lds((const AS1 unsigned*)g, (AS3 unsigned*)l, 16, 0, 0);
}

// ---- w [784][50265] f32  ->  wT [50304][832] bf16 (transposed, zero padded)
__global__ __launch_bounds__(256) void wconv(const float* __restrict__ w, u16* __restrict__ wT){
  __shared__ float tile[64][65];
  const int n0 = blockIdx.x * 64;
  const int k0 = blockIdx.y * 64;
  const int t = threadIdx.x;
#pragma unroll
  for (int i = 0; i < 16; ++i){
    int idx = t + i*256;
    int kk = idx >> 6, nn = idx & 63;
    int k = k0 + kk, n = n0 + nn;
    float v = 0.f;
    if (k < DCAT && n < VOCAB_N) v = w[(size_t)k*VOCAB_N + n];
    tile[kk][nn] = v;
  }
  __syncthreads();
#pragma unroll
  for (int i = 0; i < 4; ++i){
    int idx = t + i*256;
    int nn = idx >> 4, ks = (idx & 15) * 4;
    u16x4 o;
    o[0] = f2bf(tile[ks+0][nn]);
    o[1] = f2bf(tile[ks+1][nn]);
    o[2] = f2bf(tile[ks+2][nn]);
    o[3] = f2bf(tile[ks+3][nn]);
    *reinterpret_cast<u16x4*>(&wT[(size_t)(n0+nn)*KX + k0 + ks]) = o;
  }
}

// ---- embedding gather into x bf16 [2048][832]; zero the pe/pad columns
__global__ __launch_bounds__(256) void gather_emb(const int* __restrict__ code, const float* __restrict__ emb,
                                                  u16* __restrict__ x){
  const int row = blockIdx.x;
  const int c = code[row];
  const float* e = emb + (size_t)c * DEMB;
  for (int i = threadIdx.x; i < KX; i += 256){
    u16 v = 0;
    if (i < DEMB) v = f2bf(e[i]);
    x[(size_t)row*KX + i] = v;
  }
}

// ---- masked average of token embeddings into node rows
__global__ __launch_bounds__(256) void node_avg(const int* __restrict__ code, const int* __restrict__ pos,
                                                const int* __restrict__ attn, const float* __restrict__ emb,
                                                u16* __restrict__ x){
  const int row = blockIdx.x;
  const int b = row >> 9, i = row & (SEQ-1);
  if (pos[row] != 0) return;            // block-uniform exit
  __shared__ unsigned char sel[SEQ];
  __shared__ int crow[SEQ];
  __shared__ int cnt_s;
  const int t = threadIdx.x;
  if (t == 0) cnt_s = 0;
  __syncthreads();
  int local = 0;
  for (int j = t; j < SEQ; j += 256){
    bool s = (pos[b*SEQ + j] >= 2) && (attn[((size_t)(b*SEQ + i))*SEQ + j] != 0);
    sel[j] = s ? 1 : 0;
    crow[j] = code[b*SEQ + j];
    local += s ? 1 : 0;
  }
  atomicAdd(&cnt_s, local);
  __syncthreads();
  const float scale = 1.0f / ((float)cnt_s + 1e-10f);
  for (int d = t; d < DEMB; d += 256){
    float acc = 0.f;
    for (int j = 0; j < SEQ; ++j){
      if (sel[j]) acc += emb[(size_t)crow[j]*DEMB + d];   // wave-uniform branch
    }
    x[(size_t)row*KX + d] = f2bf(acc * scale);
  }
}

// ---- build M (row-major) and MT (= M^T, N-major B-operand), pe col 0 = 1/deg
__global__ __launch_bounds__(256) void build_M(const int* __restrict__ attn, u16* __restrict__ M,
                                               u16* __restrict__ MT, u16* __restrict__ x){
  const int row = blockIdx.x;
  const int b = row >> 9, i = row & (SEQ-1);
  __shared__ float arow[SEQ];
  __shared__ int deg_s;
  const int t = threadIdx.x;
  if (t == 0) deg_s = 0;
  __syncthreads();
  int local = 0;
  for (int j = t; j < SEQ; j += 256){
    int a = (j == i) ? 1 : ((attn[((size_t)(b*SEQ + i))*SEQ + j] != 0) ? 1 : 0);
    arow[j] = (float)a;
    local += a;
  }
  atomicAdd(&deg_s, local);
  __syncthreads();
  const float inv = 1.0f / (float)deg_s;     // deg >= 1 (self loop)
  for (int j = t; j < SEQ; j += 256){
    u16 m = f2bf(arow[j] * inv);
    M [((size_t)(b*SEQ + i))*SEQ + j] = m;
    MT[((size_t)(b*SEQ + j))*SEQ + i] = m;
  }
  if (t == 0) x[(size_t)row*KX + DEMB] = f2bf(inv);   // diag(M^1) = 1/deg
}

// ---- one PE chain step: P_out = A @ M (B given as MT, N-major), diag -> x col 768+step
__global__ __launch_bounds__(256) void pe_step(const u16* __restrict__ A, const u16* __restrict__ Bn,
                                               u16* __restrict__ P, u16* __restrict__ x, int step){
  const int m0 = blockIdx.x * 128;
  const int n0 = blockIdx.y * 128;
  const int b  = blockIdx.z;
  const u16* Ab = A  + (size_t)b*SEQ*SEQ;
  const u16* Bb = Bn + (size_t)b*SEQ*SEQ;
  __shared__ __align__(16) u16 Al[128*64];
  __shared__ __align__(16) u16 Bl[128*64];
  const int t = threadIdx.x, lane = t & 63, w = t >> 6;
  const int wr = w >> 1, wc = w & 1;
  f32x4 acc[4][4] = {};
  const int lr8 = lane >> 3;
  const int lk8 = (lane & 7) * 8;
  for (int k0 = 0; k0 < SEQ; k0 += 64){
    __syncthreads();
#pragma unroll
    for (int c = 0; c < 4; ++c){
      int chunk = w*4 + c;
      int r = chunk*8 + lr8;
      gl_lds16(Ab + (size_t)(m0 + r)*SEQ + k0 + lk8, Al + chunk*512);
      gl_lds16(Bb + (size_t)(n0 + r)*SEQ + k0 + lk8, Bl + chunk*512);
    }
    asm volatile("s_waitcnt vmcnt(0)" ::: "memory");
    __syncthreads();
#pragma unroll
    for (int kin = 0; kin < 2; ++kin){
      s16x8 fa[4], fb[4];
#pragma unroll
      for (int m = 0; m < 4; ++m)
        fa[m] = *reinterpret_cast<const s16x8*>(Al + (wr*64 + m*16 + (lane & 15))*64 + kin*32 + (lane >> 4)*8);
#pragma unroll
      for (int n = 0; n < 4; ++n)
        fb[n] = *reinterpret_cast<const s16x8*>(Bl + (wc*64 + n*16 + (lane & 15))*64 + kin*32 + (lane >> 4)*8);
#pragma unroll
      for (int m = 0; m < 4; ++m)
#pragma unroll
        for (int n = 0; n < 4; ++n)
          acc[m][n] = __builtin_amdgcn_mfma_f32_16x16x32_bf16(fa[m], fb[n], acc[m][n], 0, 0, 0);
    }
  }
#pragma unroll
  for (int m = 0; m < 4; ++m)
#pragma unroll
   for (int n = 0; n < 4; ++n)
#pragma unroll
    for (int r = 0; r < 4; ++r){
      int gm = m0 + wr*64 + m*16 + (lane >> 4)*4 + r;
      int gn = n0 + wc*64 + n*16 + (lane & 15);
      u16 bv = f2bf(acc[m][n][r]);
      P[((size_t)(b*SEQ + gm))*SEQ + gn] = bv;
      if (gm == gn) x[((size_t)(b*SEQ + gm))*KX + DEMB + step] = bv;
    }
}

// ---- fast GEMM: out[mt<nmt rows][50265] = x @ wT^T + bias
__global__ __launch_bounds__(256) void gemm_fast(const u16* __restrict__ X, const u16* __restrict__ WT,
                                                 const float* __restrict__ bias, float* __restrict__ out,
                                                 int nmt){
  const int bid = blockIdx.x;
  const int mt = bid % nmt, nt = bid / nmt;   // same-nt blocks consecutive -> share w panel in L2
  const int m0 = mt*128, n0 = nt*128;
  __shared__ __align__(16) u16 Al[128*64];
  __shared__ __align__(16) u16 Bl[128*64];
  const int t = threadIdx.x, lane = t & 63, w = t >> 6;
  const int wr = w >> 1, wc = w & 1;
  f32x4 acc[4][4] = {};
  const int lr8 = lane >> 3;
  const int lk8 = (lane & 7) * 8;
  for (int k0 = 0; k0 < KX; k0 += 64){
    __syncthreads();
#pragma unroll
    for (int c = 0; c < 4; ++c){
      int chunk = w*4 + c;
      int r = chunk*8 + lr8;
      gl_lds16(X  + (size_t)(m0 + r)*KX + k0 + lk8, Al + chunk*512);
      gl_lds16(WT + (size_t)(n0 + r)*KX + k0 + lk8, Bl + chunk*512);
    }
    asm volatile("s_waitcnt vmcnt(0)" ::: "memory");
    __syncthreads();
#pragma unroll
    for (int kin = 0; kin < 2; ++kin){
      s16x8 fa[4], fb[4];
#pragma unroll
      for (int m = 0; m < 4; ++m)
        fa[m] = *reinterpret_cast<const s16x8*>(Al + (wr*64 + m*16 + (lane & 15))*64 + kin*32 + (lane >> 4)*8);
#pragma unroll
      for (int n = 0; n < 4; ++n)
        fb[n] = *reinterpret_cast<const s16x8*>(Bl + (wc*64 + n*16 + (lane & 15))*64 + kin*32 + (lane >> 4)*8);
#pragma unroll
      for (int m = 0; m < 4; ++m)
#pragma unroll
        for (int n = 0; n < 4; ++n)
          acc[m][n] = __builtin_amdgcn_mfma_f32_16x16x32_bf16(fa[m], fb[n], acc[m][n], 0, 0, 0);
    }
  }
#pragma unroll
  for (int m = 0; m < 4; ++m)
#pragma unroll
   for (int n = 0; n < 4; ++n)
#pragma unroll
    for (int r = 0; r < 4; ++r){
      int gm = m0 + wr*64 + m*16 + (lane >> 4)*4 + r;
      int gn = n0 + wc*64 + n*16 + (lane & 15);
      if (gn < VOCAB_N)
        out[(size_t)gm*VOCAB_N + gn] = acc[m][n][r] + bias[gn];
    }
}

// ---- slow GEMM for rows 1536..2047: reads w [784][50265] f32 directly,
//      reg-staged transpose+bf16-convert into XOR-swizzled LDS
__global__ __launch_bounds__(256) void gemm_slow(const u16* __restrict__ X, const float* __restrict__ W,
                                                 const float* __restrict__ bias, float* __restrict__ out){
  const int bid = blockIdx.x;
  const int mt = 12 + (bid & 3), nt = bid >> 2;
  const int m0 = mt*128, n0 = nt*128;
  __shared__ __align__(16) u16 Al[128*64];
  __shared__ __align__(16) u16 Bl[128*64];
  char* Blc = reinterpret_cast<char*>(Bl);
  const int t = threadIdx.x, lane = t & 63, w = t >> 6;
  const int wr = w >> 1, wc = w & 1;
  f32x4 acc[4][4] = {};
  const int lr8 = lane >> 3;
  const int lk8 = (lane & 7) * 8;
  const int nn  = t & 127;
  const int kk0 = (t >> 7) * 32;
  const int ng  = n0 + nn;
  const bool nok = (ng < VOCAB_N);
  const int bsw = nn*128;
  const int xsw = (nn & 15) << 3;
  for (int k0 = 0; k0 < KX; k0 += 64){
    __syncthreads();
#pragma unroll
    for (int c = 0; c < 4; ++c){
      int chunk = w*4 + c;
      int r = chunk*8 + lr8;
      gl_lds16(X + (size_t)(m0 + r)*KX + k0 + lk8, Al + chunk*512);
    }
#pragma unroll
    for (int i = 0; i < 16; ++i){
      int k = kk0 + 2*i;
      int gk = k0 + k;
      float f0 = (nok && gk     < DCAT) ? W[(size_t)gk    *VOCAB_N + ng] : 0.f;
      float f1 = (nok && gk + 1 < DCAT) ? W[(size_t)(gk+1)*VOCAB_N + ng] : 0.f;
      unsigned pk = (unsigned)f2bf(f0) | ((unsigned)f2bf(f1) << 16);
      *reinterpret_cast<unsigned*>(Blc + bsw + ((k*2) ^ xsw)) = pk;
    }
    asm volatile("s_waitcnt vmcnt(0)" ::: "memory");
    __syncthreads();
#pragma unroll
    for (int kin = 0; kin < 2; ++kin){
      s16x8 fa[4], fb[4];
#pragma unroll
      for (int m = 0; m < 4; ++m)
        fa[m] = *reinterpret_cast<const s16x8*>(Al + (wr*64 + m*16 + (lane & 15))*64 + kin*32 + (lane >> 4)*8);
#pragma unroll
      for (int n = 0; n < 4; ++n){
        int row = wc*64 + n*16 + (lane & 15);
        int kb  = kin*64 + (lane >> 4)*16;
        int rsw = (row & 15) << 3;
        u64 h0 = *reinterpret_cast<const u64*>(Blc + row*128 + ((kb    ) ^ rsw));
        u64 h1 = *reinterpret_cast<const u64*>(Blc + row*128 + ((kb + 8) ^ rsw));
        struct U128 { u64 a, b; } u{h0, h1};
        fb[n] = __builtin_bit_cast(s16x8, u);
      }
#pragma unroll
      for (int m = 0; m < 4; ++m)
#pragma unroll
        for (int n = 0; n < 4; ++n)
          acc[m][n] = __builtin_amdgcn_mfma_f32_16x16x32_bf16(fa[m], fb[n], acc[m][n], 0, 0, 0);
    }
  }
#pragma unroll
  for (int m = 0; m < 4; ++m)
#pragma unroll
   for (int n = 0; n < 4; ++n)
#pragma unroll
    for (int r = 0; r < 4; ++r){
      int gm = m0 + wr*64 + m*16 + (lane >> 4)*4 + r;
      int gn = n0 + wc*64 + n*16 + (lane & 15);
      if (gn < VOCAB_N)
        out[(size_t)gm*VOCAB_N + gn] = acc[m][n][r] + bias[gn];
    }
}

extern "C" void kernel_launch(void* const* d_in, const int* in_sizes, int n_in,
                              void* d_out, int out_size, void* d_ws, size_t ws_size,
                              hipStream_t stream) {
  (void)in_sizes; (void)n_in; (void)out_size;
  const int*   code = (const int*)d_in[0];
  const int*   pos  = (const int*)d_in[1];
  const int*   attn = (const int*)d_in[2];
  const float* emb  = (const float*)d_in[3];
  const float* wlin = (const float*)d_in[4];
  const float* bias = (const float*)d_in[5];
  float* out = (float*)d_out;

  const size_t WT_ELE = (size_t)NPAD * KX;            // 41,852,928 u16
  const size_t X_ELE  = (size_t)OUT_ROWS * KX;        //  1,703,936 u16
  const size_t PE_ELE = (size_t)NBATCH * SEQ * SEQ;   //  1,048,576 u16
  const size_t OUT_ELE = (size_t)OUT_ROWS * VOCAB_N;  // f32 elems in d_out
  const size_t need_full = (WT_ELE + X_ELE + 4*PE_ELE) * sizeof(u16);

  u16 *wT, *x, *M, *MT, *P0, *P1;
  const bool compact = (ws_size < need_full);
  if (!compact){
    wT = (u16*)d_ws;
    x  = wT + WT_ELE;
  } else {
    // wT lives in the tail of d_out (rows >= 1632); overwritten only by gemm_slow afterwards
    wT = (u16*)d_out + (OUT_ELE*2 - WT_ELE);
    x  = (u16*)d_ws;
  }
  M  = x  + X_ELE;
  MT = M  + PE_ELE;
  P0 = MT + PE_ELE;
  P1 = P0 + PE_ELE;

  wconv     <<<dim3(NPAD/64, KX/64), 256, 0, stream>>>(wlin, wT);
  gather_emb<<<NBATCH*SEQ, 256, 0, stream>>>(code, emb, x);
  node_avg  <<<NBATCH*SEQ, 256, 0, stream>>>(code, pos, attn, emb, x);
  build_M   <<<NBATCH*SEQ, 256, 0, stream>>>(attn, M, MT, x);

  const u16* A = M;
  u16* Pb[2] = {P0, P1};
  for (int s = 1; s <= 15; ++s){
    u16* Pn = Pb[(s-1) & 1];
    pe_step<<<dim3(4,4,NBATCH), 256, 0, stream>>>(A, MT, Pn, x, s);
    A = Pn;
  }

  if (!compact){
    gemm_fast<<<(NPAD/128)*16, 256, 0, stream>>>(x, wT, bias, out, 16);
  } else {
    gemm_fast<<<(NPAD/128)*12, 256, 0, stream>>>(x, wT, bias, out, 12);  // rows 0..1535
    gemm_slow<<<(NPAD/128)*4,  256, 0, stream>>>(x, wlin, bias, out);    // rows 1536..2047
  }
}

// Round 5
// 1151.050 us; speedup vs baseline: 1.1224x; 1.1224x over previous
//
#include <hip/hip_runtime.h>

#define VOCAB_N 50265
#define NPAD    50304
#define KX      832     // padded D_CAT (784 -> 13*64)
#define DEMB    768
#define DCAT    784
#define SEQ     512
#define NBATCH  4
#define OUT_ROWS 2048
#define PE_ELE  ((size_t)NBATCH*SEQ*SEQ)

typedef unsigned short u16;
typedef unsigned long long u64;
typedef short s16x8 __attribute__((ext_vector_type(8)));
typedef float f32x4 __attribute__((ext_vector_type(4)));
typedef u16   u16x4 __attribute__((ext_vector_type(4)));

#define AS1 __attribute__((address_space(1)))
#define AS3 __attribute__((address_space(3)))

__device__ __forceinline__ u16 f2bf(float f){
  unsigned u = __builtin_bit_cast(unsigned, f);
  u = (u + 0x7FFFu + ((u >> 16) & 1u)) >> 16;
  return (u16)u;
}
__device__ __forceinline__ float bf2f(u16 h){
  return __builtin_bit_cast(float, (unsigned)h << 16);
}
__device__ __forceinline__ void gl_lds16(const void* g, void* l){
  __builtin_amdgcn_global_load_lds((const AS1 unsigned*)g, (AS3 unsigned*)l, 16, 0, 0);
}
// bijective XCD chunking (m204): physical bid -> logical id contiguous per XCD
__device__ __forceinline__ int xcd_remap(int bid, int nwg){
  int q = nwg >> 3, r = nwg & 7;
  int xc = bid & 7, i = bid >> 3;
  int base = xc < r ? xc*(q+1) : r*(q+1) + (xc - r)*q;
  return base + i;
}

// ---- w [784][50265] f32 -> wT [50304][832] bf16 (transposed, zero padded)
__global__ __launch_bounds__(256) void wconv(const float* __restrict__ w, u16* __restrict__ wT){
  __shared__ float tile[64][65];
  const int n0 = blockIdx.x * 64;
  const int k0 = blockIdx.y * 64;
  const int t = threadIdx.x;
#pragma unroll
  for (int i = 0; i < 16; ++i){
    int idx = t + i*256;
    int kk = idx >> 6, nn = idx & 63;
    int k = k0 + kk, n = n0 + nn;
    float v = 0.f;
    if (k < DCAT && n < VOCAB_N) v = w[(size_t)k*VOCAB_N + n];
    tile[kk][nn] = v;
  }
  __syncthreads();
#pragma unroll
  for (int i = 0; i < 4; ++i){
    int idx = t + i*256;
    int nn = idx >> 4, ks = (idx & 15) * 4;
    u16x4 o;
    o[0] = f2bf(tile[ks+0][nn]);
    o[1] = f2bf(tile[ks+1][nn]);
    o[2] = f2bf(tile[ks+2][nn]);
    o[3] = f2bf(tile[ks+3][nn]);
    *reinterpret_cast<u16x4*>(&wT[(size_t)(n0+nn)*KX + k0 + ks]) = o;
  }
}

// ---- embedding gather into x bf16 [2048][832]; zero pe/pad cols
__global__ __launch_bounds__(256) void gather_emb(const int* __restrict__ code, const float* __restrict__ emb,
                                                  u16* __restrict__ x){
  const int row = blockIdx.x;
  const int c = code[row];
  const float* e = emb + (size_t)c * DEMB;
  for (int i = threadIdx.x; i < KX; i += 256){
    u16 v = 0;
    if (i < DEMB) v = f2bf(e[i]);
    x[(size_t)row*KX + i] = v;
  }
}

// ---- masked average of token embeddings into node rows
__global__ __launch_bounds__(256) void node_avg(const int* __restrict__ code, const int* __restrict__ pos,
                                                const int* __restrict__ attn, const float* __restrict__ emb,
                                                u16* __restrict__ x){
  const int row = blockIdx.x;
  const int b = row >> 9, i = row & (SEQ-1);
  if (pos[row] != 0) return;
  __shared__ unsigned char sel[SEQ];
  __shared__ int crow[SEQ];
  __shared__ int cnt_s;
  const int t = threadIdx.x;
  if (t == 0) cnt_s = 0;
  __syncthreads();
  int local = 0;
  for (int j = t; j < SEQ; j += 256){
    bool s = (pos[b*SEQ + j] >= 2) && (attn[((size_t)(b*SEQ + i))*SEQ + j] != 0);
    sel[j] = s ? 1 : 0;
    crow[j] = code[b*SEQ + j];
    local += s ? 1 : 0;
  }
  atomicAdd(&cnt_s, local);
  __syncthreads();
  const float scale = 1.0f / ((float)cnt_s + 1e-10f);
  for (int d = t; d < DEMB; d += 256){
    float acc = 0.f;
    for (int j = 0; j < SEQ; ++j){
      if (sel[j]) acc += emb[(size_t)crow[j]*DEMB + d];
    }
    x[(size_t)row*KX + d] = f2bf(acc * scale);
  }
}

// ---- build M (row-major) and MT (N-major), pe col 768 = 1/deg = diag(M^1)
__global__ __launch_bounds__(256) void build_M(const int* __restrict__ attn, u16* __restrict__ M,
                                               u16* __restrict__ MT, u16* __restrict__ x){
  const int row = blockIdx.x;
  const int b = row >> 9, i = row & (SEQ-1);
  __shared__ float arow[SEQ];
  __shared__ int deg_s;
  const int t = threadIdx.x;
  if (t == 0) deg_s = 0;
  __syncthreads();
  int local = 0;
  for (int j = t; j < SEQ; j += 256){
    int a = (j == i) ? 1 : ((attn[((size_t)(b*SEQ + i))*SEQ + j] != 0) ? 1 : 0);
    arow[j] = (float)a;
    local += a;
  }
  atomicAdd(&deg_s, local);
  __syncthreads();
  const float inv = 1.0f / (float)deg_s;
  for (int j = t; j < SEQ; j += 256){
    u16 m = f2bf(arow[j] * inv);
    M [((size_t)(b*SEQ + i))*SEQ + j] = m;
    MT[((size_t)(b*SEQ + j))*SEQ + i] = m;
  }
  if (t == 0) x[(size_t)row*KX + DEMB] = f2bf(inv);
}

// ---- power step: C = A @ M (B given as MT, N-major), 64x64 tile, diag -> x[xcol]
__global__ __launch_bounds__(256) void pe_pow(const u16* __restrict__ A, const u16* __restrict__ Bn,
                                              u16* __restrict__ C, u16* __restrict__ x, int xcol){
  const int m0 = blockIdx.x * 64, n0 = blockIdx.y * 64, b = blockIdx.z;
  const u16* Ab = A  + (size_t)b*SEQ*SEQ;
  const u16* Bb = Bn + (size_t)b*SEQ*SEQ;
  __shared__ __align__(16) u16 Al[64*64];
  __shared__ __align__(16) u16 Bl[64*64];
  const int t = threadIdx.x, lane = t & 63, w = t >> 6;
  const int wr = w >> 1, wc = w & 1;
  f32x4 acc[2][2] = {};
  const int srow = lane >> 3;                    // row within 8-row chunk
  const int scol = ((lane & 7) ^ srow) * 8;      // inverse-swizzled global col (u16)
  for (int k0 = 0; k0 < SEQ; k0 += 64){
    __syncthreads();
#pragma unroll
    for (int c = 0; c < 2; ++c){
      int chunk = w*2 + c;
      int r = chunk*8 + srow;
      gl_lds16(Ab + (size_t)(m0 + r)*SEQ + k0 + scol, Al + chunk*512);
      gl_lds16(Bb + (size_t)(n0 + r)*SEQ + k0 + scol, Bl + chunk*512);
    }
    asm volatile("s_waitcnt vmcnt(0)" ::: "memory");
    __syncthreads();
#pragma unroll
    for (int kin = 0; kin < 2; ++kin){
      s16x8 fa[2], fb[2];
      const int kb = kin*64 + (lane >> 4)*16;
#pragma unroll
      for (int m = 0; m < 2; ++m){
        int r = wr*32 + m*16 + (lane & 15);
        fa[m] = *reinterpret_cast<const s16x8*>((const char*)Al + r*128 + (kb ^ ((r & 7) << 4)));
      }
#pragma unroll
      for (int n = 0; n < 2; ++n){
        int r = wc*32 + n*16 + (lane & 15);
        fb[n] = *reinterpret_cast<const s16x8*>((const char*)Bl + r*128 + (kb ^ ((r & 7) << 4)));
      }
#pragma unroll
      for (int m = 0; m < 2; ++m)
#pragma unroll
        for (int n = 0; n < 2; ++n)
          acc[m][n] = __builtin_amdgcn_mfma_f32_16x16x32_bf16(fa[m], fb[n], acc[m][n], 0, 0, 0);
    }
  }
#pragma unroll
  for (int m = 0; m < 2; ++m)
#pragma unroll
   for (int n = 0; n < 2; ++n)
#pragma unroll
    for (int r = 0; r < 4; ++r){
      int gm = m0 + wr*32 + m*16 + (lane >> 4)*4 + r;
      int gn = n0 + wc*32 + n*16 + (lane & 15);
      u16 bv = f2bf(acc[m][n][r]);
      C[((size_t)(b*SEQ + gm))*SEQ + gn] = bv;
      if (gm == gn) x[(size_t)(b*SEQ + gm)*KX + xcol] = bv;
    }
}

// ---- transpose P8 -> P8T (row i of P8T = col i of P8)
__global__ __launch_bounds__(256) void transpose_k(const u16* __restrict__ in, u16* __restrict__ outp){
  const int i0 = blockIdx.x*64, j0 = blockIdx.y*64, b = blockIdx.z;
  const u16* ib = in   + (size_t)b*SEQ*SEQ;
  u16*       ob = outp + (size_t)b*SEQ*SEQ;
  __shared__ u16 tile[64][66];
  const int t = threadIdx.x;
#pragma unroll
  for (int it = 0; it < 2; ++it){
    int jj = it*32 + (t >> 3), ii = (t & 7)*8;
    s16x8 v = *reinterpret_cast<const s16x8*>(ib + (size_t)(j0+jj)*SEQ + i0 + ii);
#pragma unroll
    for (int q = 0; q < 8; ++q) tile[jj][ii+q] = (u16)v[q];
  }
  __syncthreads();
#pragma unroll
  for (int it = 0; it < 2; ++it){
    int ii = it*32 + (t >> 3), jj8 = (t & 7)*8;
    u16 tmp[8];
#pragma unroll
    for (int q = 0; q < 8; ++q) tmp[q] = tile[jj8+q][ii];
    *reinterpret_cast<s16x8*>(ob + (size_t)(i0+ii)*SEQ + j0 + jj8) = *reinterpret_cast<s16x8*>(tmp);
  }
}

// ---- diag(M^(8+a)) = <row_i(M^a), row_i(P8T)>, a=1..8 -> x cols 776..783
__global__ __launch_bounds__(256) void pe_dots(const u16* __restrict__ M, const u16* __restrict__ pw,
                                               const u16* __restrict__ p8t, u16* __restrict__ x){
  const int row = blockIdx.x;           // b*512 + i
  const int lane = threadIdx.x & 63, w = threadIdx.x >> 6;
  const u16* t8 = p8t + (size_t)row*SEQ;
  s16x8 vb = *reinterpret_cast<const s16x8*>(t8 + lane*8);
#pragma unroll
  for (int s = 0; s < 2; ++s){
    int a = 1 + w + s*4;
    const u16* Pa = (a == 1) ? (M + (size_t)row*SEQ) : (pw + (size_t)(a-2)*PE_ELE + (size_t)row*SEQ);
    s16x8 va = *reinterpret_cast<const s16x8*>(Pa + lane*8);
    float acc = 0.f;
#pragma unroll
    for (int q = 0; q < 8; ++q) acc += bf2f((u16)va[q]) * bf2f((u16)vb[q]);
#pragma unroll
    for (int m = 32; m; m >>= 1) acc += __shfl_xor(acc, m, 64);
    if (lane == 0) x[(size_t)row*KX + DEMB + 8 + (a-1)] = f2bf(acc);
  }
}

// ---- fast GEMM: out = x @ wT^T + bias (swizzled staging, XCD-chunked blocks)
__global__ __launch_bounds__(256) void gemm_fast(const u16* __restrict__ X, const u16* __restrict__ WT,
                                                 const float* __restrict__ bias, float* __restrict__ out,
                                                 int nmt, int nwg){
  const int lid = xcd_remap(blockIdx.x, nwg);
  const int mt = lid % nmt, nt = lid / nmt;
  const int m0 = mt*128, n0 = nt*128;
  __shared__ __align__(16) u16 Al[128*64];
  __shared__ __align__(16) u16 Bl[128*64];
  const int t = threadIdx.x, lane = t & 63, w = t >> 6;
  const int wr = w >> 1, wc = w & 1;
  f32x4 acc[4][4] = {};
  const int srow = lane >> 3;
  const int scol = ((lane & 7) ^ srow) * 8;      // inverse-swizzled global col
  for (int k0 = 0; k0 < KX; k0 += 64){
    __syncthreads();
#pragma unroll
    for (int c = 0; c < 4; ++c){
      int chunk = w*4 + c;
      int r = chunk*8 + srow;
      gl_lds16(X  + (size_t)(m0 + r)*KX + k0 + scol, Al + chunk*512);
      gl_lds16(WT + (size_t)(n0 + r)*KX + k0 + scol, Bl + chunk*512);
    }
    asm volatile("s_waitcnt vmcnt(0)" ::: "memory");
    __syncthreads();
#pragma unroll
    for (int kin = 0; kin < 2; ++kin){
      s16x8 fa[4], fb[4];
      const int kb = kin*64 + (lane >> 4)*16;
#pragma unroll
      for (int m = 0; m < 4; ++m){
        int r = wr*64 + m*16 + (lane & 15);
        fa[m] = *reinterpret_cast<const s16x8*>((const char*)Al + r*128 + (kb ^ ((r & 7) << 4)));
      }
#pragma unroll
      for (int n = 0; n < 4; ++n){
        int r = wc*64 + n*16 + (lane & 15);
        fb[n] = *reinterpret_cast<const s16x8*>((const char*)Bl + r*128 + (kb ^ ((r & 7) << 4)));
      }
#pragma unroll
      for (int m = 0; m < 4; ++m)
#pragma unroll
        for (int n = 0; n < 4; ++n)
          acc[m][n] = __builtin_amdgcn_mfma_f32_16x16x32_bf16(fa[m], fb[n], acc[m][n], 0, 0, 0);
    }
  }
#pragma unroll
  for (int m = 0; m < 4; ++m)
#pragma unroll
   for (int n = 0; n < 4; ++n)
#pragma unroll
    for (int r = 0; r < 4; ++r){
      int gm = m0 + wr*64 + m*16 + (lane >> 4)*4 + r;
      int gn = n0 + wc*64 + n*16 + (lane & 15);
      if (gn < VOCAB_N)
        out[(size_t)gm*VOCAB_N + gn] = acc[m][n][r] + bias[gn];
    }
}

// ---- slow GEMM rows 1536..2047 (compact mode): reads w f32 directly
__global__ __launch_bounds__(256) void gemm_slow(const u16* __restrict__ X, const float* __restrict__ W,
                                                 const float* __restrict__ bias, float* __restrict__ out,
                                                 int nwg){
  const int lid = xcd_remap(blockIdx.x, nwg);
  const int mt = 12 + (lid & 3), nt = lid >> 2;
  const int m0 = mt*128, n0 = nt*128;
  __shared__ __align__(16) u16 Al[128*64];
  __shared__ __align__(16) u16 Bl[128*64];
  char* Blc = reinterpret_cast<char*>(Bl);
  const int t = threadIdx.x, lane = t & 63, w = t >> 6;
  const int wr = w >> 1, wc = w & 1;
  f32x4 acc[4][4] = {};
  const int srow = lane >> 3;
  const int scol = ((lane & 7) ^ srow) * 8;
  const int nn  = t & 127;
  const int kk0 = (t >> 7) * 32;
  const int ng  = n0 + nn;
  const bool nok = (ng < VOCAB_N);
  const int bsw = nn*128;
  const int xsw = (nn & 15) << 3;
  for (int k0 = 0; k0 < KX; k0 += 64){
    __syncthreads();
#pragma unroll
    for (int c = 0; c < 4; ++c){
      int chunk = w*4 + c;
      int r = chunk*8 + srow;
      gl_lds16(X + (size_t)(m0 + r)*KX + k0 + scol, Al + chunk*512);
    }
#pragma unroll
    for (int i = 0; i < 16; ++i){
      int k = kk0 + 2*i;
      int gk = k0 + k;
      float f0 = (nok && gk     < DCAT) ? W[(size_t)gk    *VOCAB_N + ng] : 0.f;
      float f1 = (nok && gk + 1 < DCAT) ? W[(size_t)(gk+1)*VOCAB_N + ng] : 0.f;
      unsigned pk = (unsigned)f2bf(f0) | ((unsigned)f2bf(f1) << 16);
      *reinterpret_cast<unsigned*>(Blc + bsw + ((k*2) ^ xsw)) = pk;
    }
    asm volatile("s_waitcnt vmcnt(0)" ::: "memory");
    __syncthreads();
#pragma unroll
    for (int kin = 0; kin < 2; ++kin){
      s16x8 fa[4], fb[4];
      const int kb = kin*64 + (lane >> 4)*16;
#pragma unroll
      for (int m = 0; m < 4; ++m){
        int r = wr*64 + m*16 + (lane & 15);
        fa[m] = *reinterpret_cast<const s16x8*>((const char*)Al + r*128 + (kb ^ ((r & 7) << 4)));
      }
#pragma unroll
      for (int n = 0; n < 4; ++n){
        int row = wc*64 + n*16 + (lane & 15);
        int kbb = kin*64 + (lane >> 4)*16;
        int rsw = (row & 15) << 3;
        u64 h0 = *reinterpret_cast<const u64*>(Blc + row*128 + ((kbb    ) ^ rsw));
        u64 h1 = *reinterpret_cast<const u64*>(Blc + row*128 + ((kbb + 8) ^ rsw));
        struct U128 { u64 a, b; } u{h0, h1};
        fb[n] = __builtin_bit_cast(s16x8, u);
      }
#pragma unroll
      for (int m = 0; m < 4; ++m)
#pragma unroll
        for (int n = 0; n < 4; ++n)
          acc[m][n] = __builtin_amdgcn_mfma_f32_16x16x32_bf16(fa[m], fb[n], acc[m][n], 0, 0, 0);
    }
  }
#pragma unroll
  for (int m = 0; m < 4; ++m)
#pragma unroll
   for (int n = 0; n < 4; ++n)
#pragma unroll
    for (int r = 0; r < 4; ++r){
      int gm = m0 + wr*64 + m*16 + (lane >> 4)*4 + r;
      int gn = n0 + wc*64 + n*16 + (lane & 15);
      if (gn < VOCAB_N)
        out[(size_t)gm*VOCAB_N + gn] = acc[m][n][r] + bias[gn];
    }
}

extern "C" void kernel_launch(void* const* d_in, const int* in_sizes, int n_in,
                              void* d_out, int out_size, void* d_ws, size_t ws_size,
                              hipStream_t stream) {
  (void)in_sizes; (void)n_in; (void)out_size;
  const int*   code = (const int*)d_in[0];
  const int*   pos  = (const int*)d_in[1];
  const int*   attn = (const int*)d_in[2];
  const float* emb  = (const float*)d_in[3];
  const float* wlin = (const float*)d_in[4];
  const float* bias = (const float*)d_in[5];
  float* out = (float*)d_out;

  const size_t WT_ELE  = (size_t)NPAD * KX;
  const size_t X_ELE   = (size_t)OUT_ROWS * KX;
  const size_t OUT_ELE = (size_t)OUT_ROWS * VOCAB_N;
  // full layout: wT + x + M + MT + P2..P8 + P8T
  const size_t need_full = (WT_ELE + X_ELE + 2*PE_ELE + 8*PE_ELE) * sizeof(u16);

  u16 *wT, *x, *M, *MT, *pw, *p8t;
  const bool compact = (ws_size < need_full);
  if (!compact){
    wT  = (u16*)d_ws;
    x   = wT + WT_ELE;
    M   = x  + X_ELE;
    MT  = M  + PE_ELE;
    pw  = MT + PE_ELE;           // P2..P8 (7 buffers)
    p8t = pw + 7*PE_ELE;
  } else {
    // ws: x + M + MT (7.4 MB). d_out head: P2..P8 + P8T (16.8 MB, rows < 45,
    // overwritten by gemm_fast afterwards). d_out tail: wT (rows >= 1632,
    // read by gemm_fast, overwritten only by gemm_slow).
    x   = (u16*)d_ws;
    M   = x + X_ELE;
    MT  = M + PE_ELE;
    pw  = (u16*)d_out;
    p8t = pw + 7*PE_ELE;
    wT  = (u16*)d_out + (OUT_ELE*2 - WT_ELE);
  }

  wconv     <<<dim3(NPAD/64, KX/64), 256, 0, stream>>>(wlin, wT);
  gather_emb<<<NBATCH*SEQ, 256, 0, stream>>>(code, emb, x);
  node_avg  <<<NBATCH*SEQ, 256, 0, stream>>>(code, pos, attn, emb, x);
  build_M   <<<NBATCH*SEQ, 256, 0, stream>>>(attn, M, MT, x);

  // powers M^2..M^8 (diag -> x cols 769..775)
  const u16* A = M;
  for (int c = 2; c <= 8; ++c){
    u16* C = pw + (size_t)(c-2)*PE_ELE;
    pe_pow<<<dim3(8,8,NBATCH), 256, 0, stream>>>(A, MT, C, x, DEMB + (c-1));
    A = C;
  }
  transpose_k<<<dim3(8,8,NBATCH), 256, 0, stream>>>(pw + 6*PE_ELE, p8t);
  pe_dots<<<NBATCH*SEQ, 256, 0, stream>>>(M, pw, p8t, x);

  if (!compact){
    const int nwg = (NPAD/128)*16;
    gemm_fast<<<nwg, 256, 0, stream>>>(x, wT, bias, out, 16, nwg);
  } else {
    const int nwg_f = (NPAD/128)*12;
    gemm_fast<<<nwg_f, 256, 0, stream>>>(x, wT, bias, out, 12, nwg_f);
    const int nwg_s = (NPAD/128)*4;
    gemm_slow<<<nwg_s, 256, 0, stream>>>(x, wlin, bias, out, nwg_s);
  }
}

// Round 6
// 1001.318 us; speedup vs baseline: 1.2902x; 1.1495x over previous
//
#include <hip/hip_runtime.h>

#define VOCAB_N 50265
#define NPAD    50304
#define KX      832     // padded D_CAT (784 -> 13*64)
#define DEMB    768
#define DCAT    784
#define SEQ     512
#define NBATCH  4
#define OUT_ROWS 2048
#define PE_ELE  ((size_t)NBATCH*SEQ*SEQ)

typedef unsigned short u16;
typedef unsigned long long u64;
typedef short s16x8 __attribute__((ext_vector_type(8)));
typedef float f32x4 __attribute__((ext_vector_type(4)));
typedef u16   u16x4 __attribute__((ext_vector_type(4)));

#define AS1 __attribute__((address_space(1)))
#define AS3 __attribute__((address_space(3)))

__device__ __forceinline__ u16 f2bf(float f){
  unsigned u = __builtin_bit_cast(unsigned, f);
  u = (u + 0x7FFFu + ((u >> 16) & 1u)) >> 16;
  return (u16)u;
}
__device__ __forceinline__ float bf2f(u16 h){
  return __builtin_bit_cast(float, (unsigned)h << 16);
}
__device__ __forceinline__ void gl_lds16(const void* g, void* l){
  __builtin_amdgcn_global_load_lds((const AS1 unsigned*)g, (AS3 unsigned*)l, 16, 0, 0);
}
// bijective XCD chunking (m204)
__device__ __forceinline__ int xcd_remap(int bid, int nwg){
  int q = nwg >> 3, r = nwg & 7;
  int xc = bid & 7, i = bid >> 3;
  int base = xc < r ? xc*(q+1) : r*(q+1) + (xc - r)*q;
  return base + i;
}

// ---- w [784][50265] f32 -> wT [50304][832] bf16 (transposed, zero padded)
__global__ __launch_bounds__(256) void wconv(const float* __restrict__ w, u16* __restrict__ wT){
  __shared__ float tile[64][65];
  const int n0 = blockIdx.x * 64;
  const int k0 = blockIdx.y * 64;
  const int t = threadIdx.x;
#pragma unroll
  for (int i = 0; i < 16; ++i){
    int idx = t + i*256;
    int kk = idx >> 6, nn = idx & 63;
    int k = k0 + kk, n = n0 + nn;
    float v = 0.f;
    if (k < DCAT && n < VOCAB_N) v = w[(size_t)k*VOCAB_N + n];
    tile[kk][nn] = v;
  }
  __syncthreads();
#pragma unroll
  for (int i = 0; i < 4; ++i){
    int idx = t + i*256;
    int nn = idx >> 4, ks = (idx & 15) * 4;
    u16x4 o;
    o[0] = f2bf(tile[ks+0][nn]);
    o[1] = f2bf(tile[ks+1][nn]);
    o[2] = f2bf(tile[ks+2][nn]);
    o[3] = f2bf(tile[ks+3][nn]);
    *reinterpret_cast<u16x4*>(&wT[(size_t)(n0+nn)*KX + k0 + ks]) = o;
  }
}

// ---- embedding gather into x bf16 [2048][832]; zero pe/pad cols
__global__ __launch_bounds__(256) void gather_emb(const int* __restrict__ code, const float* __restrict__ emb,
                                                  u16* __restrict__ x){
  const int row = blockIdx.x;
  const int c = code[row];
  const float* e = emb + (size_t)c * DEMB;
  for (int i = threadIdx.x; i < KX; i += 256){
    u16 v = 0;
    if (i < DEMB) v = f2bf(e[i]);
    x[(size_t)row*KX + i] = v;
  }
}

// ---- masked average: inverted loop, coalesced float4 row accumulation
__global__ __launch_bounds__(256) void node_avg(const int* __restrict__ code, const int* __restrict__ pos,
                                                const int* __restrict__ attn, const float* __restrict__ emb,
                                                u16* __restrict__ x){
  const int row = blockIdx.x;
  const int b = row >> 9;
  if (pos[row] != 0) return;            // block-uniform exit
  __shared__ int list[SEQ];             // selected rows as emb element offsets
  __shared__ int cnt_s;
  const int t = threadIdx.x;
  if (t == 0) cnt_s = 0;
  __syncthreads();
  for (int j = t; j < SEQ; j += 256){
    if (pos[b*SEQ + j] >= 2 && attn[(size_t)row*SEQ + j] != 0){
      int slot = atomicAdd(&cnt_s, 1);
      list[slot] = code[b*SEQ + j] * DEMB;
    }
  }
  __syncthreads();
  const int cnt = cnt_s;
  const float scale = 1.0f / ((float)cnt + 1e-10f);
  if (t < DEMB/4){
    f32x4 acc = {};
    int k = 0;
    for (; k + 4 <= cnt; k += 4){
      f32x4 v0 = reinterpret_cast<const f32x4*>(emb + list[k+0])[t];
      f32x4 v1 = reinterpret_cast<const f32x4*>(emb + list[k+1])[t];
      f32x4 v2 = reinterpret_cast<const f32x4*>(emb + list[k+2])[t];
      f32x4 v3 = reinterpret_cast<const f32x4*>(emb + list[k+3])[t];
      acc += v0; acc += v1; acc += v2; acc += v3;
    }
    for (; k < cnt; ++k)
      acc += reinterpret_cast<const f32x4*>(emb + list[k])[t];
    u16x4 o;
#pragma unroll
    for (int q = 0; q < 4; ++q) o[q] = f2bf(acc[q] * scale);
    *reinterpret_cast<u16x4*>(&x[(size_t)row*KX + t*4]) = o;
  }
}

// ---- build M (row-major, coalesced only), pe col 768 = 1/deg = diag(M^1)
__global__ __launch_bounds__(256) void build_M(const int* __restrict__ attn, u16* __restrict__ M,
                                               u16* __restrict__ x){
  const int row = blockIdx.x;
  const int b = row >> 9, i = row & (SEQ-1);
  __shared__ int deg_s;
  __shared__ float arow[SEQ];
  const int t = threadIdx.x;
  if (t == 0) deg_s = 0;
  __syncthreads();
  int local = 0;
  for (int j = t; j < SEQ; j += 256){
    int a = (j == i) ? 1 : ((attn[((size_t)(b*SEQ + i))*SEQ + j] != 0) ? 1 : 0);
    arow[j] = (float)a;
    local += a;
  }
  atomicAdd(&deg_s, local);
  __syncthreads();
  const float inv = 1.0f / (float)deg_s;
  for (int j = t; j < SEQ; j += 256)
    M[((size_t)(b*SEQ + i))*SEQ + j] = f2bf(arow[j] * inv);
  if (t == 0) x[(size_t)row*KX + DEMB] = f2bf(inv);
}

// ---- tiled transpose within batch: out[i][j] = in[j][i]
__global__ __launch_bounds__(256) void transpose_k(const u16* __restrict__ in, u16* __restrict__ outp){
  const int i0 = blockIdx.x*64, j0 = blockIdx.y*64, b = blockIdx.z;
  const u16* ib = in   + (size_t)b*SEQ*SEQ;
  u16*       ob = outp + (size_t)b*SEQ*SEQ;
  __shared__ u16 tile[64][66];
  const int t = threadIdx.x;
#pragma unroll
  for (int it = 0; it < 2; ++it){
    int jj = it*32 + (t >> 3), ii = (t & 7)*8;
    s16x8 v = *reinterpret_cast<const s16x8*>(ib + (size_t)(j0+jj)*SEQ + i0 + ii);
#pragma unroll
    for (int q = 0; q < 8; ++q) tile[jj][ii+q] = (u16)v[q];
  }
  __syncthreads();
#pragma unroll
  for (int it = 0; it < 2; ++it){
    int ii = it*32 + (t >> 3), jj8 = (t & 7)*8;
    u16 tmp[8];
#pragma unroll
    for (int q = 0; q < 8; ++q) tmp[q] = tile[jj8+q][ii];
    *reinterpret_cast<s16x8*>(ob + (size_t)(i0+ii)*SEQ + j0 + jj8) = *reinterpret_cast<s16x8*>(tmp);
  }
}

#define PP_STAGE(kt, bf) do{ const int _k0 = (kt)*64;                              \
  for (int _c = 0; _c < 2; ++_c){                                                  \
    int _ch = w*2 + _c; int _r = _ch*8 + srow;                                     \
    gl_lds16(Ab + (size_t)(m0 + _r)*SEQ + _k0 + scol, &Al[bf][_ch*512]);           \
    gl_lds16(Bb + (size_t)(n0 + _r)*SEQ + _k0 + scol, &Bl[bf][_ch*512]); } }while(0)

// ---- power step: C = A @ M (B given as MT, N-major), 64x64 tile, dbuf, diag -> x[xcol]
__global__ __launch_bounds__(256) void pe_pow(const u16* __restrict__ A, const u16* __restrict__ Bn,
                                              u16* __restrict__ C, u16* __restrict__ x, int xcol){
  const int m0 = blockIdx.x * 64, n0 = blockIdx.y * 64, b = blockIdx.z;
  const u16* Ab = A  + (size_t)b*SEQ*SEQ;
  const u16* Bb = Bn + (size_t)b*SEQ*SEQ;
  __shared__ __align__(16) u16 Al[2][64*64];
  __shared__ __align__(16) u16 Bl[2][64*64];
  const int t = threadIdx.x, lane = t & 63, w = t >> 6;
  const int wr = w >> 1, wc = w & 1;
  f32x4 acc[2][2] = {};
  const int srow = lane >> 3;
  const int scol = ((lane & 7) ^ srow) * 8;
  PP_STAGE(0, 0);
  asm volatile("s_waitcnt vmcnt(0)" ::: "memory");
  __syncthreads();
  for (int kt = 0; kt < SEQ/64; ++kt){
    const int cur = kt & 1;
    if (kt + 1 < SEQ/64) PP_STAGE(kt+1, cur^1);
#pragma unroll
    for (int kin = 0; kin < 2; ++kin){
      s16x8 fa[2], fb[2];
      const int kb = kin*64 + (lane >> 4)*16;
#pragma unroll
      for (int m = 0; m < 2; ++m){
        int r = wr*32 + m*16 + (lane & 15);
        fa[m] = *reinterpret_cast<const s16x8*>((const char*)&Al[cur][0] + r*128 + (kb ^ ((r & 7) << 4)));
      }
#pragma unroll
      for (int n = 0; n < 2; ++n){
        int r = wc*32 + n*16 + (lane & 15);
        fb[n] = *reinterpret_cast<const s16x8*>((const char*)&Bl[cur][0] + r*128 + (kb ^ ((r & 7) << 4)));
      }
#pragma unroll
      for (int m = 0; m < 2; ++m)
#pragma unroll
        for (int n = 0; n < 2; ++n)
          acc[m][n] = __builtin_amdgcn_mfma_f32_16x16x32_bf16(fa[m], fb[n], acc[m][n], 0, 0, 0);
    }
    asm volatile("s_waitcnt vmcnt(0)" ::: "memory");
    __syncthreads();
  }
#pragma unroll
  for (int m = 0; m < 2; ++m)
#pragma unroll
   for (int n = 0; n < 2; ++n)
#pragma unroll
    for (int r = 0; r < 4; ++r){
      int gm = m0 + wr*32 + m*16 + (lane >> 4)*4 + r;
      int gn = n0 + wc*32 + n*16 + (lane & 15);
      u16 bv = f2bf(acc[m][n][r]);
      C[((size_t)(b*SEQ + gm))*SEQ + gn] = bv;
      if (gm == gn) x[(size_t)(b*SEQ + gm)*KX + xcol] = bv;
    }
}

// ---- diag(M^(8+a)) = <row_i(M^a), row_i(P8T)>, a=1..8 -> x cols 776..783
__global__ __launch_bounds__(256) void pe_dots(const u16* __restrict__ M, const u16* __restrict__ pw,
                                               const u16* __restrict__ p8t, u16* __restrict__ x){
  const int row = blockIdx.x;
  const int lane = threadIdx.x & 63, w = threadIdx.x >> 6;
  const u16* t8 = p8t + (size_t)row*SEQ;
  s16x8 vb = *reinterpret_cast<const s16x8*>(t8 + lane*8);
#pragma unroll
  for (int s = 0; s < 2; ++s){
    int a = 1 + w + s*4;
    const u16* Pa = (a == 1) ? (M + (size_t)row*SEQ) : (pw + (size_t)(a-2)*PE_ELE + (size_t)row*SEQ);
    s16x8 va = *reinterpret_cast<const s16x8*>(Pa + lane*8);
    float acc = 0.f;
#pragma unroll
    for (int q = 0; q < 8; ++q) acc += bf2f((u16)va[q]) * bf2f((u16)vb[q]);
#pragma unroll
    for (int m = 32; m; m >>= 1) acc += __shfl_xor(acc, m, 64);
    if (lane == 0) x[(size_t)row*KX + DEMB + 8 + (a-1)] = f2bf(acc);
  }
}

#define GF_STAGE(kt, bf) do{ const int _k0 = (kt)*64;                              \
  for (int _c = 0; _c < 4; ++_c){                                                  \
    int _ch = w*4 + _c; int _r = _ch*8 + srow;                                     \
    gl_lds16(X  + (size_t)(m0 + _r)*KX + _k0 + scol, &Al[bf][_ch*512]);            \
    gl_lds16(WT + (size_t)(n0 + _r)*KX + _k0 + scol, &Bl[bf][_ch*512]); } }while(0)

// ---- fast GEMM: out = x @ wT^T + bias (dbuf, swizzled staging, XCD-chunked)
__global__ __launch_bounds__(256) void gemm_fast(const u16* __restrict__ X, const u16* __restrict__ WT,
                                                 const float* __restrict__ bias, float* __restrict__ out,
                                                 int nmt, int nwg){
  const int lid = xcd_remap(blockIdx.x, nwg);
  const int mt = lid % nmt, nt = lid / nmt;
  const int m0 = mt*128, n0 = nt*128;
  __shared__ __align__(16) u16 Al[2][128*64];
  __shared__ __align__(16) u16 Bl[2][128*64];
  const int t = threadIdx.x, lane = t & 63, w = t >> 6;
  const int wr = w >> 1, wc = w & 1;
  f32x4 acc[4][4] = {};
  const int srow = lane >> 3;
  const int scol = ((lane & 7) ^ srow) * 8;
  GF_STAGE(0, 0);
  asm volatile("s_waitcnt vmcnt(0)" ::: "memory");
  __syncthreads();
  const int NKT = KX/64;   // 13
  for (int kt = 0; kt < NKT; ++kt){
    const int cur = kt & 1;
    if (kt + 1 < NKT) GF_STAGE(kt+1, cur^1);
#pragma unroll
    for (int kin = 0; kin < 2; ++kin){
      s16x8 fa[4], fb[4];
      const int kb = kin*64 + (lane >> 4)*16;
#pragma unroll
      for (int m = 0; m < 4; ++m){
        int r = wr*64 + m*16 + (lane & 15);
        fa[m] = *reinterpret_cast<const s16x8*>((const char*)&Al[cur][0] + r*128 + (kb ^ ((r & 7) << 4)));
      }
#pragma unroll
      for (int n = 0; n < 4; ++n){
        int r = wc*64 + n*16 + (lane & 15);
        fb[n] = *reinterpret_cast<const s16x8*>((const char*)&Bl[cur][0] + r*128 + (kb ^ ((r & 7) << 4)));
      }
#pragma unroll
      for (int m = 0; m < 4; ++m)
#pragma unroll
        for (int n = 0; n < 4; ++n)
          acc[m][n] = __builtin_amdgcn_mfma_f32_16x16x32_bf16(fa[m], fb[n], acc[m][n], 0, 0, 0);
    }
    asm volatile("s_waitcnt vmcnt(0)" ::: "memory");
    __syncthreads();
  }
#pragma unroll
  for (int m = 0; m < 4; ++m)
#pragma unroll
   for (int n = 0; n < 4; ++n)
#pragma unroll
    for (int r = 0; r < 4; ++r){
      int gm = m0 + wr*64 + m*16 + (lane >> 4)*4 + r;
      int gn = n0 + wc*64 + n*16 + (lane & 15);
      if (gn < VOCAB_N)
        out[(size_t)gm*VOCAB_N + gn] = acc[m][n][r] + bias[gn];
    }
}

// ---- slow GEMM rows 1536..2047 (compact mode): reads w f32 directly
__global__ __launch_bounds__(256) void gemm_slow(const u16* __restrict__ X, const float* __restrict__ W,
                                                 const float* __restrict__ bias, float* __restrict__ out,
                                                 int nwg){
  const int lid = xcd_remap(blockIdx.x, nwg);
  const int mt = 12 + (lid & 3), nt = lid >> 2;
  const int m0 = mt*128, n0 = nt*128;
  __shared__ __align__(16) u16 Al[128*64];
  __shared__ __align__(16) u16 Bl[128*64];
  char* Blc = reinterpret_cast<char*>(Bl);
  const int t = threadIdx.x, lane = t & 63, w = t >> 6;
  const int wr = w >> 1, wc = w & 1;
  f32x4 acc[4][4] = {};
  const int srow = lane >> 3;
  const int scol = ((lane & 7) ^ srow) * 8;
  const int nn  = t & 127;
  const int kk0 = (t >> 7) * 32;
  const int ng  = n0 + nn;
  const bool nok = (ng < VOCAB_N);
  const int bsw = nn*128;
  const int xsw = (nn & 15) << 3;
  for (int k0 = 0; k0 < KX; k0 += 64){
    __syncthreads();
    for (int c = 0; c < 4; ++c){
      int chunk = w*4 + c;
      int r = chunk*8 + srow;
      gl_lds16(X + (size_t)(m0 + r)*KX + k0 + scol, Al + chunk*512);
    }
#pragma unroll
    for (int i = 0; i < 16; ++i){
      int k = kk0 + 2*i;
      int gk = k0 + k;
      float f0 = (nok && gk     < DCAT) ? W[(size_t)gk    *VOCAB_N + ng] : 0.f;
      float f1 = (nok && gk + 1 < DCAT) ? W[(size_t)(gk+1)*VOCAB_N + ng] : 0.f;
      unsigned pk = (unsigned)f2bf(f0) | ((unsigned)f2bf(f1) << 16);
      *reinterpret_cast<unsigned*>(Blc + bsw + ((k*2) ^ xsw)) = pk;
    }
    asm volatile("s_waitcnt vmcnt(0)" ::: "memory");
    __syncthreads();
#pragma unroll
    for (int kin = 0; kin < 2; ++kin){
      s16x8 fa[4], fb[4];
      const int kb = kin*64 + (lane >> 4)*16;
#pragma unroll
      for (int m = 0; m < 4; ++m){
        int r = wr*64 + m*16 + (lane & 15);
        fa[m] = *reinterpret_cast<const s16x8*>((const char*)Al + r*128 + (kb ^ ((r & 7) << 4)));
      }
#pragma unroll
      for (int n = 0; n < 4; ++n){
        int row = wc*64 + n*16 + (lane & 15);
        int kbb = kin*64 + (lane >> 4)*16;
        int rsw = (row & 15) << 3;
        u64 h0 = *reinterpret_cast<const u64*>(Blc + row*128 + ((kbb    ) ^ rsw));
        u64 h1 = *reinterpret_cast<const u64*>(Blc + row*128 + ((kbb + 8) ^ rsw));
        struct U128 { u64 a, b; } u{h0, h1};
        fb[n] = __builtin_bit_cast(s16x8, u);
      }
#pragma unroll
      for (int m = 0; m < 4; ++m)
#pragma unroll
        for (int n = 0; n < 4; ++n)
          acc[m][n] = __builtin_amdgcn_mfma_f32_16x16x32_bf16(fa[m], fb[n], acc[m][n], 0, 0, 0);
    }
  }
#pragma unroll
  for (int m = 0; m < 4; ++m)
#pragma unroll
   for (int n = 0; n < 4; ++n)
#pragma unroll
    for (int r = 0; r < 4; ++r){
      int gm = m0 + wr*64 + m*16 + (lane >> 4)*4 + r;
      int gn = n0 + wc*64 + n*16 + (lane & 15);
      if (gn < VOCAB_N)
        out[(size_t)gm*VOCAB_N + gn] = acc[m][n][r] + bias[gn];
    }
}

extern "C" void kernel_launch(void* const* d_in, const int* in_sizes, int n_in,
                              void* d_out, int out_size, void* d_ws, size_t ws_size,
                              hipStream_t stream) {
  (void)in_sizes; (void)n_in; (void)out_size;
  const int*   code = (const int*)d_in[0];
  const int*   pos  = (const int*)d_in[1];
  const int*   attn = (const int*)d_in[2];
  const float* emb  = (const float*)d_in[3];
  const float* wlin = (const float*)d_in[4];
  const float* bias = (const float*)d_in[5];
  float* out = (float*)d_out;

  const size_t WT_ELE  = (size_t)NPAD * KX;
  const size_t X_ELE   = (size_t)OUT_ROWS * KX;
  const size_t OUT_ELE = (size_t)OUT_ROWS * VOCAB_N;
  const size_t need_full = (WT_ELE + X_ELE + 2*PE_ELE + 8*PE_ELE) * sizeof(u16);

  u16 *wT, *x, *M, *MT, *pw, *p8t;
  const bool compact = (ws_size < need_full);
  if (!compact){
    wT  = (u16*)d_ws;
    x   = wT + WT_ELE;
    M   = x  + X_ELE;
    MT  = M  + PE_ELE;
    pw  = MT + PE_ELE;           // P2..P8 (7 buffers)
    p8t = pw + 7*PE_ELE;
  } else {
    x   = (u16*)d_ws;
    M   = x + X_ELE;
    MT  = M + PE_ELE;
    pw  = (u16*)d_out;                              // d_out head, clobbered by gemm_fast later
    p8t = pw + 7*PE_ELE;
    wT  = (u16*)d_out + (OUT_ELE*2 - WT_ELE);       // d_out tail, clobbered only by gemm_slow
  }

  wconv      <<<dim3(NPAD/64, KX/64), 256, 0, stream>>>(wlin, wT);
  gather_emb <<<NBATCH*SEQ, 256, 0, stream>>>(code, emb, x);
  node_avg   <<<NBATCH*SEQ, 256, 0, stream>>>(code, pos, attn, emb, x);
  build_M    <<<NBATCH*SEQ, 256, 0, stream>>>(attn, M, x);
  transpose_k<<<dim3(8,8,NBATCH), 256, 0, stream>>>(M, MT);

  const u16* A = M;
  for (int c = 2; c <= 8; ++c){
    u16* C = pw + (size_t)(c-2)*PE_ELE;
    pe_pow<<<dim3(8,8,NBATCH), 256, 0, stream>>>(A, MT, C, x, DEMB + (c-1));
    A = C;
  }
  transpose_k<<<dim3(8,8,NBATCH), 256, 0, stream>>>(pw + 6*PE_ELE, p8t);
  pe_dots<<<NBATCH*SEQ, 256, 0, stream>>>(M, pw, p8t, x);

  if (!compact){
    const int nwg = (NPAD/128)*16;
    gemm_fast<<<nwg, 256, 0, stream>>>(x, wT, bias, out, 16, nwg);
  } else {
    const int nwg_f = (NPAD/128)*12;
    gemm_fast<<<nwg_f, 256, 0, stream>>>(x, wT, bias, out, 12, nwg_f);
    const int nwg_s = (NPAD/128)*4;
    gemm_slow<<<nwg_s, 256, 0, stream>>>(x, wlin, bias, out, nwg_s);
  }
}